// Round 19
// baseline (118.342 us; speedup 1.0000x reference)
//
#include <hip/hip_runtime.h>

typedef _Float16 f16;
typedef __attribute__((ext_vector_type(8))) _Float16 f16x8;
typedef __attribute__((ext_vector_type(4))) _Float16 f16x4;
typedef __attribute__((ext_vector_type(2))) __fp16 h16x2;
typedef __attribute__((ext_vector_type(4))) float f32x4;

#define NH 12
#define DHD 64
#define NB 8
#define NSEQ 1024
#define DMODEL 768
#define BHN (NB*NH)            // 96
#define ROWS_PER (BHN*NSEQ)    // 98304

#define MFMA(a,b,c) __builtin_amdgcn_mfma_f32_16x16x32_f16(a,b,c,0,0,0)

__device__ __forceinline__ void gload16(const void* g, void* l) {
  __builtin_amdgcn_global_load_lds(
      (__attribute__((address_space(1))) void*)(g),
      (__attribute__((address_space(3))) void*)(l), 16, 0, 0);
}

// one fused cast: hs (nhs) + Wq|Wk|Wv -> Wf, Wo -> Wof (nw each) + rope table
__global__ __launch_bounds__(256) void cast_all_kernel(const float* __restrict__ hs,
                                                       const float* __restrict__ Wq,
                                                       const float* __restrict__ Wk,
                                                       const float* __restrict__ Wv,
                                                       const float* __restrict__ Wo,
                                                       f16* __restrict__ Xf,
                                                       f16* __restrict__ Wf,
                                                       f16* __restrict__ Wof,
                                                       float2* __restrict__ rtab,
                                                       int nhs, int nw) {
  int i = (blockIdx.x * blockDim.x + threadIdx.x) * 4;
  const float* src;
  f16* dst;
  if (i < nhs) {
    src = hs + i; dst = Xf + i;
  } else {
    int j = i - nhs;
    int which = j / nw;
    int off = j - which*nw;
    src = ((which == 0) ? Wq : (which == 1) ? Wk : (which == 2) ? Wv : Wo) + off;
    dst = ((which < 3) ? (Wf + (size_t)which*nw) : Wof) + off;
  }
  float4 v = *(const float4*)src;
  f16x4 o = {(f16)v.x, (f16)v.y, (f16)v.z, (f16)v.w};
  *(f16x4*)dst = o;
  if (blockIdx.x == 0) {
    for (int e = threadIdx.x; e < 512; e += 256) {
      int pos = e >> 4, k = e & 15;
      float ang = (float)pos * __expf((float)k * (-4.605170185988091f / 16.0f));
      float sn, cs;
      __sincosf(ang, &sn, &cs);
      rtab[e] = make_float2(cs, sn);
    }
  }
}

// C = A(MxK) * B(NxK)^T, fp16, BK=64, XOR-swizzled, DOUBLE-BUFFERED LDS.
// Both modes: 128x64 tile, 512 threads = 8 waves (4 row x 2 col), wave-tile
// 32x32, 48KB LDS -> 3 blocks/CU; grids are exact multiples of capacity
// (tail-free): MODE0 grid 768 (64x12), MODE1 grid 2304 (64x36).
// MODE 0: fp32 row-major C.
// MODE 1: bx<24 (Q,K): fused rms-norm (cross-wave LDS exchange for the
//   64-dim row sum) + scale + rope(table) -> fp16 [qk][bh][ns][64], Q
//   pre-scaled by log2(e). bx>=24 (V): rms-norm + LDS transpose ->
//   Vout [bh][64][1024] fp16.
template<int MODE>
__global__ __launch_bounds__(512) void gemm_bt(const f16* __restrict__ A,
                                               const f16* __restrict__ B,
                                               float* __restrict__ Cout,
                                               f16* __restrict__ QKout,
                                               f16* __restrict__ Vout,
                                               const int* __restrict__ pos_ids,
                                               const float* __restrict__ q_scale,
                                               const float* __restrict__ k_scale,
                                               const float2* __restrict__ rtab,
                                               int M, int N, int K) {
  constexpr int ABUF = 8192;                  // 128x64 f16
  constexpr int BBUF = 4096;                  // 64x64 f16
  __shared__ __align__(16) f16 SH[2*ABUF + 2*BBUF];   // 48KB
  const int tid = threadIdx.x;                // 0..511
  const int w = tid >> 6, l = tid & 63;
  const int wr = w >> 1, wc = w & 1;          // 4 x 2 wave grid
  const int g = l >> 4, i16 = l & 15;

  int bx, by;
  {
    int id = blockIdx.x;
    const int nbx = (MODE == 1) ? 36 : 12;
    const int chunk = (MODE == 1) ? 288 : 96;
    int idp = (id & 7) * chunk + (id >> 3);
    by = idp / nbx; bx = idp - by * nbx;
  }

  const f32x4 fzero = {0.f, 0.f, 0.f, 0.f};
  f32x4 acc[2][2];
#pragma unroll
  for (int i = 0; i < 2; i++)
#pragma unroll
    for (int j = 0; j < 2; j++) acc[i][j] = fzero;

  const int srow = tid >> 3;                  // 0..63
  const int schunk = (tid & 7) ^ (srow & 7);
  const size_t arow = (size_t)(by*128 + srow)*K + schunk*8;
  const size_t brow = (size_t)(bx*64 + srow)*K + schunk*8;

  const int nt = K / 64;  // 12
#define STAGE(buf, k0)                                                          \
  {                                                                             \
    char* AlB = (char*)(SH + (buf)*ABUF) + w*1024;                              \
    char* BlB = (char*)(SH + 2*ABUF + (buf)*BBUF) + w*1024;                     \
    gload16(A + arow + (k0), AlB);                                              \
    gload16(A + arow + (size_t)64*K + (k0), AlB + 8192);                        \
    gload16(B + brow + (k0), BlB);                                              \
  }

  STAGE(0, 0);
  __syncthreads();
  for (int t = 0; t < nt; ++t) {
    const int buf = t & 1;
    if (t + 1 < nt) STAGE(buf ^ 1, (t + 1)*64);
    const f16* Ac = SH + buf*ABUF;
    const f16* Bc = SH + 2*ABUF + buf*BBUF;
#pragma unroll
    for (int kk = 0; kk < 2; ++kk) {
      f16x8 af[2], bfr[2];
#pragma unroll
      for (int i = 0; i < 2; i++)
        af[i] = *(const f16x8*)(Ac + (wr*32 + i*16 + i16)*64 + ((kk*4 + g) ^ (i16 & 7))*8);
#pragma unroll
      for (int j = 0; j < 2; j++)
        bfr[j] = *(const f16x8*)(Bc + (wc*32 + j*16 + i16)*64 + ((kk*4 + g) ^ (i16 & 7))*8);
#pragma unroll
      for (int i = 0; i < 2; i++)
#pragma unroll
        for (int j = 0; j < 2; j++)
          acc[i][j] = MFMA(af[i], bfr[j], acc[i][j]);
    }
    __syncthreads();
  }
#undef STAGE

  const int m0 = by*128 + wr*32;
  const int n0 = bx*64 + wc*32;
  if constexpr (MODE == 0) {
#pragma unroll
    for (int i = 0; i < 2; i++)
#pragma unroll
      for (int j = 0; j < 2; j++)
#pragma unroll
        for (int r = 0; r < 4; r++) {
          int m = m0 + i*16 + g*4 + r;
          int n = n0 + j*16 + i16;
          Cout[(size_t)m*N + n] = acc[i][j][r];
        }
  } else {
    // partial sum-of-squares over this wave's 32 cols, reduced over i16 lanes
    float ssv2[2][4];
#pragma unroll
    for (int i = 0; i < 2; i++) {
      f32x4 ssv = fzero;
#pragma unroll
      for (int j = 0; j < 2; j++)
#pragma unroll
        for (int r = 0; r < 4; r++) ssv[r] += acc[i][j][r]*acc[i][j][r];
#pragma unroll
      for (int d = 1; d < 16; d <<= 1)
#pragma unroll
        for (int r = 0; r < 4; r++) ssv[r] += __shfl_xor(ssv[r], d);
#pragma unroll
      for (int r = 0; r < 4; r++) ssv2[i][r] = ssv[r];
    }

    if (bx >= 24) {
      // V: rms-norm + LDS transpose -> Vout [bh][64][1024]
      const int h = bx - 24;
      const int bb = by >> 3;
      const int ns0 = (by & 7) * 128;
      f16* Lt = SH;                          // [64 dh][136 ns]
      float* part = (float*)(SH + 20480);    // [2][128]
      if (i16 == 0) {
#pragma unroll
        for (int i = 0; i < 2; i++)
#pragma unroll
          for (int r = 0; r < 4; r++)
            part[wc*128 + wr*32 + i*16 + g*4 + r] = ssv2[i][r];
      }
      __syncthreads();
#pragma unroll
      for (int i = 0; i < 2; i++)
#pragma unroll
        for (int r = 0; r < 4; r++) {
          int ml = wr*32 + i*16 + g*4 + r;
          float tot = ssv2[i][r] + part[(wc^1)*128 + ml];
          float rinv = rsqrtf(tot*(1.0f/64.0f) + 1e-6f);
#pragma unroll
          for (int j = 0; j < 2; j++)
            Lt[(wc*32 + j*16 + i16)*136 + ml] = (f16)(acc[i][j][r]*rinv);
        }
      __syncthreads();
      const int dh = tid >> 3, nsc = (tid & 7) * 16;
      f16* dst = Vout + ((size_t)((bb*NH + h)*64 + dh))*1024 + ns0 + nsc;
      const f16* ls = Lt + dh*136 + nsc;
      *(uint4*)(dst)     = *(const uint4*)(ls);
      *(uint4*)(dst + 8) = *(const uint4*)(ls + 8);
    } else {
      // Q/K: rms-norm + scale + rope; wc=0 -> d[0,32) with pos.x,
      // wc=1 -> d[32,64) with pos.y. Q pre-scaled by log2(e).
      const int qkv = bx / 12;
      const int h = bx - qkv*12;
      const float* scp = (qkv == 0) ? q_scale : k_scale;
      float scl[2];
#pragma unroll
      for (int j = 0; j < 2; j++) {
        scl[j] = scp[wc*32 + j*16 + i16];
        if (qkv == 0) scl[j] *= 1.4426950408889634f;
      }
      float* part = (float*)SH;              // [2][128]
      if (i16 == 0) {
#pragma unroll
        for (int i = 0; i < 2; i++)
#pragma unroll
          for (int r = 0; r < 4; r++)
            part[wc*128 + wr*32 + i*16 + g*4 + r] = ssv2[i][r];
      }
      __syncthreads();
      const float2* rt = rtab + i16;
#pragma unroll
      for (int i = 0; i < 2; i++)
#pragma unroll
        for (int r = 0; r < 4; r++) {
          int ml = wr*32 + i*16 + g*4 + r;
          int m = by*128 + ml;
          int bb = m >> 10, ns = m & 1023;
          float tot = ssv2[i][r] + part[(wc^1)*128 + ml];
          float rinv = rsqrtf(tot*(1.0f/64.0f) + 1e-6f);
          int2 pp = *(const int2*)(pos_ids + ((size_t)bb*NSEQ + ns)*2);
          float2 tt = rt[(wc ? pp.y : pp.x)*16];
          float x0 = acc[i][0][r]*rinv*scl[0];
          float x1 = acc[i][1][r]*rinv*scl[1];
          size_t row = ((size_t)qkv*BHN + bb*NH + h)*NSEQ + ns;
          f16* ob = QKout + row*64 + wc*32;
          ob[i16]      = (f16)(x0*tt.x - x1*tt.y);
          ob[16 + i16] = (f16)(x1*tt.x + x0*tt.y);
        }
    }
  }
}

// sigma: LDS K-row p holds physical kv sigma(p); bit layout p={u,b,g,g,c,c} -> {u,g,g,b,c,c}
__device__ __forceinline__ int sigma_perm(int p) {
  return (p & 0x20) | ((p & 0xC) << 1) | ((p & 0x10) >> 2) | (p & 3);
}

#define FM3(a,b,c) fmaxf(fmaxf(a,b),c)

// flash attention: 1D grid 768 (= 3 blocks/CU exactly, no drain tail),
// XCD-local: xcd=id&7 owns 12 bh x 8 qb of 128 q rows. 8 waves x 16 q rows,
// KV tile = 64. exp2-domain softmax; l via MFMA(P, ones).
__global__ __launch_bounds__(512) void attn_kernel(const f16* __restrict__ QKu,
                                                   const f16* __restrict__ Vtu,
                                                   f16* __restrict__ O) {
  const int id = blockIdx.x;                 // 768 = 8 xcd * 12 bh * 8 qb
  const int xcd = id & 7, idx = id >> 3;     // idx 0..95
  const int bh = xcd*12 + (idx >> 3);
  const int q0 = (idx & 7) * 128;
  const int tid = threadIdx.x, w = tid >> 6, l = tid & 63;
  const int g = l >> 4, i16 = l & 15;
  const int g4 = g*4;
  const int sw = i16 & 7;
  const int b = bh / NH, h = bh - b*NH;

  __shared__ __align__(16) f16 Ks[2*64*64];
  __shared__ __align__(16) f16 Vs[2*64*64];

  const f16* qrow = QKu + ((size_t)bh*NSEQ + q0 + w*16 + i16)*64;
  f16x8 q0f = *(const f16x8*)(qrow + g*8);
  f16x8 q1f = *(const f16x8*)(qrow + 32 + g*8);

  const char* Kb  = (const char*)(QKu + (size_t)(BHN + bh)*NSEQ*64);
  const char* Vtb = (const char*)(Vtu + (size_t)bh*64*1024);
  const int prow0 = w*8 + (l >> 3);          // 0..63: one issue covers all rows
  const int cl = (l & 7) ^ (l >> 3);
  const char* Ksrc = Kb + sigma_perm(prow0)*128 + cl*16;
  const char* Vsrc = Vtb + prow0*2048 + cl*16;

  const f32x4 fzero = {0.f, 0.f, 0.f, 0.f};
  const f16x8 vones = {(f16)1.f,(f16)1.f,(f16)1.f,(f16)1.f,
                       (f16)1.f,(f16)1.f,(f16)1.f,(f16)1.f};
  float mR = -1e30f;
  f32x4 o[4];
  f32x4 acc_l = fzero;
#pragma unroll
  for (int t = 0; t < 4; t++) o[t] = fzero;

  int cur = 0;
  {
    gload16(Ksrc, (char*)Ks + w*1024);
    gload16(Vsrc, (char*)Vs + w*1024);
  }
  __syncthreads();

  for (int t = 0; t < 16; ++t) {
    if (t < 15) {
      gload16(Ksrc + (t+1)*8192, (char*)Ks + (cur^1)*8192 + w*1024);
      gload16(Vsrc + (t+1)*128,  (char*)Vs + (cur^1)*8192 + w*1024);
    }
    const f16* Kc = Ks + cur*4096;
    const f16* Vc = Vs + cur*4096;

    f32x4 s[4] = {fzero, fzero, fzero, fzero};
    __builtin_amdgcn_s_setprio(1);
#pragma unroll
    for (int j = 0; j < 4; ++j) {
      const f16* kr = Kc + (j*16 + i16)*64;
      f16x8 k0 = *(const f16x8*)(kr + (g ^ sw)*8);
      f16x8 k1 = *(const f16x8*)(kr + ((g^4) ^ sw)*8);
      s[j] = MFMA(k0, q0f, s[j]);
      s[j] = MFMA(k1, q1f, s[j]);
    }
    __builtin_amdgcn_s_setprio(0);

    // row max (v_max3-friendly triples) + cross-lane reduce over the i16 group
    float t0m = FM3(s[0][0], s[0][1], s[0][2]);
    float t1m = FM3(s[0][3], s[1][0], s[1][1]);
    float t2m = FM3(s[1][2], s[1][3], s[2][0]);
    float t3m = FM3(s[2][1], s[2][2], s[2][3]);
    float t4m = FM3(s[3][0], s[3][1], s[3][2]);
    float tm = fmaxf(FM3(FM3(t0m, t1m, t2m), t3m, t4m), s[3][3]);
    tm = fmaxf(tm, __shfl_xor(tm, 16));
    tm = fmaxf(tm, __shfl_xor(tm, 32));
    if (__any(tm > mR + 11.5416f)) {         // defer-max, THR = 8*log2e
      float nm = fmaxf(mR, tm);
      float fac = __builtin_amdgcn_exp2f(mR - nm);
      mR = nm;
#pragma unroll
      for (int r = 0; r < 4; ++r) {
        float fr = __shfl(fac, g4 + r);
        o[0][r] *= fr; o[1][r] *= fr; o[2][r] *= fr; o[3][r] *= fr;
        acc_l[r] *= fr;
      }
    }
#pragma unroll
    for (int j = 0; j < 4; ++j)
#pragma unroll
      for (int r = 0; r < 4; ++r) s[j][r] = __builtin_amdgcn_exp2f(s[j][r] - mR);

    // packed cvt to the PV A-fragments
    union { h16x2 h[4]; f16x8 v; } u0, u1;
    u0.h[0] = __builtin_amdgcn_cvt_pkrtz(s[0][0], s[0][1]);
    u0.h[1] = __builtin_amdgcn_cvt_pkrtz(s[0][2], s[0][3]);
    u0.h[2] = __builtin_amdgcn_cvt_pkrtz(s[1][0], s[1][1]);
    u0.h[3] = __builtin_amdgcn_cvt_pkrtz(s[1][2], s[1][3]);
    u1.h[0] = __builtin_amdgcn_cvt_pkrtz(s[2][0], s[2][1]);
    u1.h[1] = __builtin_amdgcn_cvt_pkrtz(s[2][2], s[2][3]);
    u1.h[2] = __builtin_amdgcn_cvt_pkrtz(s[3][0], s[3][1]);
    u1.h[3] = __builtin_amdgcn_cvt_pkrtz(s[3][2], s[3][3]);
    f16x8 pa0 = u0.v, pa1 = u1.v;

    __builtin_amdgcn_s_setprio(1);
#pragma unroll
    for (int t2 = 0; t2 < 4; ++t2) {
      const f16* vr = Vc + (t2*16 + i16)*64;
      f16x8 bv0 = *(const f16x8*)(vr + (g ^ sw)*8);
      f16x8 bv1 = *(const f16x8*)(vr + ((g^4) ^ sw)*8);
      o[t2] = MFMA(pa0, bv0, o[t2]);
      o[t2] = MFMA(pa1, bv1, o[t2]);
    }
    acc_l = MFMA(pa0, vones, acc_l);     // row-sum l on the matrix pipe
    acc_l = MFMA(pa1, vones, acc_l);
    __builtin_amdgcn_s_setprio(0);

    __syncthreads();
    cur ^= 1;
  }

#pragma unroll
  for (int r = 0; r < 4; ++r) {
    float invl = 1.0f / acc_l[r];
    int q = q0 + w*16 + g4 + r;
    size_t base = ((size_t)(b*NSEQ + q))*DMODEL + h*DHD;
#pragma unroll
    for (int t2 = 0; t2 < 4; ++t2)
      O[base + t2*16 + i16] = (f16)(o[t2][r] * invl);
  }
}

extern "C" void kernel_launch(void* const* d_in, const int* in_sizes, int n_in,
                              void* d_out, int out_size, void* d_ws, size_t ws_size,
                              hipStream_t stream) {
  const float* hs = (const float*)d_in[0];
  const int*   pos = (const int*)d_in[1];
  const float* Wq = (const float*)d_in[2];
  const float* Wk = (const float*)d_in[3];
  const float* Wv = (const float*)d_in[4];
  const float* Wo = (const float*)d_in[5];
  const float* qs = (const float*)d_in[6];
  const float* ks = (const float*)d_in[7];

  const int nhs = 8192*768;       // 6291456
  const int nw  = 768*768;        // 589824

  char* p = (char*)d_ws;
  f16* Xf   = (f16*)p; p += (size_t)nhs*2;
  f16* Wf   = (f16*)p; p += (size_t)3*nw*2;         // Wq|Wk|Wv
  f16* Wof  = (f16*)p; p += (size_t)nw*2;
  f16* QKpk = (f16*)p; p += (size_t)2*ROWS_PER*64*2;
  f16* Vt   = (f16*)p; p += (size_t)ROWS_PER*64*2;
  f16* Ob   = (f16*)p; p += (size_t)nhs*2;
  float2* Rtab = (float2*)p; p += 512*sizeof(float2);

  cast_all_kernel<<<(nhs + 4*nw)/1024, 256, 0, stream>>>(hs, Wq, Wk, Wv, Wo,
                                                         Xf, Wf, Wof, Rtab, nhs, nw);

  gemm_bt<1><<<2304, 512, 0, stream>>>(Xf, Wf, nullptr, QKpk, Vt,
                                       pos, qs, ks, Rtab, 8192, 2304, 768);
  attn_kernel<<<768, 512, 0, stream>>>(QKpk, Vt, Ob);
  gemm_bt<0><<<768, 512, 0, stream>>>(Ob, Wof, (float*)d_out, nullptr, nullptr,
                                      nullptr, nullptr, nullptr, nullptr, 8192, 768, 768);
}

// Round 20
// 110.435 us; speedup vs baseline: 1.0716x; 1.0716x over previous
//
#include <hip/hip_runtime.h>

typedef _Float16 f16;
typedef __attribute__((ext_vector_type(8))) _Float16 f16x8;
typedef __attribute__((ext_vector_type(4))) _Float16 f16x4;
typedef __attribute__((ext_vector_type(2))) __fp16 h16x2;
typedef __attribute__((ext_vector_type(4))) float f32x4;

#define NH 12
#define DHD 64
#define NB 8
#define NSEQ 1024
#define DMODEL 768
#define BHN (NB*NH)            // 96
#define ROWS_PER (BHN*NSEQ)    // 98304

#define MFMA(a,b,c) __builtin_amdgcn_mfma_f32_16x16x32_f16(a,b,c,0,0,0)

__device__ __forceinline__ void gload16(const void* g, void* l) {
  __builtin_amdgcn_global_load_lds(
      (__attribute__((address_space(1))) void*)(g),
      (__attribute__((address_space(3))) void*)(l), 16, 0, 0);
}

// one fused cast: hs (nhs) + Wq|Wk|Wv -> Wf, Wo -> Wof (nw each) + rope table
__global__ __launch_bounds__(256) void cast_all_kernel(const float* __restrict__ hs,
                                                       const float* __restrict__ Wq,
                                                       const float* __restrict__ Wk,
                                                       const float* __restrict__ Wv,
                                                       const float* __restrict__ Wo,
                                                       f16* __restrict__ Xf,
                                                       f16* __restrict__ Wf,
                                                       f16* __restrict__ Wof,
                                                       float2* __restrict__ rtab,
                                                       int nhs, int nw) {
  int i = (blockIdx.x * blockDim.x + threadIdx.x) * 4;
  const float* src;
  f16* dst;
  if (i < nhs) {
    src = hs + i; dst = Xf + i;
  } else {
    int j = i - nhs;
    int which = j / nw;
    int off = j - which*nw;
    src = ((which == 0) ? Wq : (which == 1) ? Wk : (which == 2) ? Wv : Wo) + off;
    dst = ((which < 3) ? (Wf + (size_t)which*nw) : Wof) + off;
  }
  float4 v = *(const float4*)src;
  f16x4 o = {(f16)v.x, (f16)v.y, (f16)v.z, (f16)v.w};
  *(f16x4*)dst = o;
  if (blockIdx.x == 0) {
    for (int e = threadIdx.x; e < 512; e += 256) {
      int pos = e >> 4, k = e & 15;
      float ang = (float)pos * __expf((float)k * (-4.605170185988091f / 16.0f));
      float sn, cs;
      __sincosf(ang, &sn, &cs);
      rtab[e] = make_float2(cs, sn);
    }
  }
}

// C = A(MxK) * B(NxK)^T, fp16, BK=64, XOR-swizzled, DOUBLE-BUFFERED LDS.
// 512 threads = 8 waves (4 row-groups x 2 col-groups), wave-tile 32 x BN/2.
// MODE 0: 128x64 tile (grid 768 = 64x12, 48KB LDS, 3 blk/CU tail-free), fp32 C
// MODE 1: 128x128 tile (grid 1152 = 18x64, 64KB LDS). bx<12 (Q,K): fused
//         rms-norm+scale+rope(table) -> fp16 [qk][bh][ns][64], Q pre-scaled
//         by log2(e). bx>=12 (V): fused rms-norm + LDS transpose ->
//         Vout [bh][64][1024] fp16.
template<int MODE>
__global__ __launch_bounds__(512) void gemm_bt(const f16* __restrict__ A,
                                               const f16* __restrict__ B,
                                               float* __restrict__ Cout,
                                               f16* __restrict__ QKout,
                                               f16* __restrict__ Vout,
                                               const int* __restrict__ pos_ids,
                                               const float* __restrict__ q_scale,
                                               const float* __restrict__ k_scale,
                                               const float2* __restrict__ rtab,
                                               int M, int N, int K) {
  constexpr int BN = (MODE == 1) ? 128 : 64;
  constexpr int NJ = BN / 32;                 // 4 or 2
  constexpr int ABUF = 8192;                  // 128x64 f16
  constexpr int BBUF = BN*64;
  __shared__ __align__(16) f16 SH[2*ABUF + 2*BBUF];
  const int tid = threadIdx.x;                // 0..511
  const int w = tid >> 6, l = tid & 63;
  const int wr = w >> 1, wc = w & 1;          // 4 x 2 wave grid
  const int g = l >> 4, i16 = l & 15;

  int bx, by;
  {
    int id = blockIdx.x;
    const int nbx = (MODE == 1) ? 18 : 12;
    const int chunk = (MODE == 1) ? 144 : 96;
    int idp = (id & 7) * chunk + (id >> 3);
    by = idp / nbx; bx = idp - by * nbx;
  }

  const f32x4 fzero = {0.f, 0.f, 0.f, 0.f};
  f32x4 acc[2][NJ];
#pragma unroll
  for (int i = 0; i < 2; i++)
#pragma unroll
    for (int j = 0; j < NJ; j++) acc[i][j] = fzero;

  const int srow = tid >> 3;                  // 0..63
  const int schunk = (tid & 7) ^ (srow & 7);
  const size_t arow = (size_t)(by*128 + srow)*K + schunk*8;
  const size_t brow = (size_t)(bx*BN + srow)*K + schunk*8;

  const int nt = K / 64;  // 12
#define STAGE(buf, k0)                                                          \
  {                                                                             \
    char* AlB = (char*)(SH + (buf)*ABUF) + w*1024;                              \
    char* BlB = (char*)(SH + 2*ABUF + (buf)*BBUF) + w*1024;                     \
    _Pragma("unroll")                                                           \
    for (int n = 0; n < 2; ++n)                                                 \
      gload16(A + arow + (size_t)(n*64)*K + (k0), AlB + n*8192);                \
    _Pragma("unroll")                                                           \
    for (int n = 0; n < BN/64; ++n)                                             \
      gload16(B + brow + (size_t)(n*64)*K + (k0), BlB + n*8192);                \
  }

  STAGE(0, 0);
  __syncthreads();
  for (int t = 0; t < nt; ++t) {
    const int buf = t & 1;
    if (t + 1 < nt) STAGE(buf ^ 1, (t + 1)*64);
    const f16* Ac = SH + buf*ABUF;
    const f16* Bc = SH + 2*ABUF + buf*BBUF;
#pragma unroll
    for (int kk = 0; kk < 2; ++kk) {
      f16x8 af[2], bfr[NJ];
#pragma unroll
      for (int i = 0; i < 2; i++)
        af[i] = *(const f16x8*)(Ac + (wr*32 + i*16 + i16)*64 + ((kk*4 + g) ^ (i16 & 7))*8);
#pragma unroll
      for (int j = 0; j < NJ; j++)
        bfr[j] = *(const f16x8*)(Bc + (wc*(BN/2) + j*16 + i16)*64 + ((kk*4 + g) ^ (i16 & 7))*8);
#pragma unroll
      for (int i = 0; i < 2; i++)
#pragma unroll
        for (int j = 0; j < NJ; j++)
          acc[i][j] = MFMA(af[i], bfr[j], acc[i][j]);
    }
    __syncthreads();
  }
#undef STAGE

  const int m0 = by*128 + wr*32;
  const int n0 = bx*BN + wc*(BN/2);
  if constexpr (MODE == 0) {
#pragma unroll
    for (int i = 0; i < 2; i++)
#pragma unroll
      for (int j = 0; j < NJ; j++)
#pragma unroll
        for (int r = 0; r < 4; r++) {
          int m = m0 + i*16 + g*4 + r;
          int n = n0 + j*16 + i16;
          Cout[(size_t)m*N + n] = acc[i][j][r];
        }
  } else {
  if (bx >= 12) {
    // V: rms-norm + LDS transpose -> Vout [bh][64][1024]
    const int h0 = (bx - 12)*2;
    const int bb = by >> 3;
    const int ns0 = (by & 7) * 128;
    f16* Lt = SH;                       // [128 dh][136]
#pragma unroll
    for (int i = 0; i < 2; i++) {
      f32x4 ssv = fzero;
#pragma unroll
      for (int j = 0; j < 4; j++)
#pragma unroll
        for (int r = 0; r < 4; r++) ssv[r] += acc[i][j][r]*acc[i][j][r];
#pragma unroll
      for (int d = 1; d < 16; d <<= 1)
#pragma unroll
        for (int r = 0; r < 4; r++) ssv[r] += __shfl_xor(ssv[r], d);
#pragma unroll
      for (int r = 0; r < 4; r++) {
        float rinv = rsqrtf(ssv[r] * (1.0f/64.0f) + 1e-6f);
        int nsl = wr*32 + i*16 + g*4 + r;
#pragma unroll
        for (int j = 0; j < 4; j++)
          Lt[(wc*64 + j*16 + i16)*136 + nsl] = (f16)(acc[i][j][r]*rinv);
      }
    }
    __syncthreads();
    const int dh = tid >> 2, q4 = tid & 3;
    f16* dst = Vout + ((size_t)((bb*NH + h0 + (dh >> 6))*64 + (dh & 63)))*1024
               + ns0 + q4*32;
    const f16* ls = Lt + dh*136 + q4*32;
#pragma unroll
    for (int e = 0; e < 4; ++e)
      *(uint4*)(dst + e*8) = *(const uint4*)(ls + e*8);
  } else {
    // fused rms-norm + scale + 2D rope (table) for Q/K; Q pre-scaled by log2e
    const int qkv = n0 / DMODEL;
    const int h = (n0 - qkv*DMODEL) >> 6;
    const float* scp = (qkv == 0) ? q_scale : k_scale;
    float scl[4];
#pragma unroll
    for (int j = 0; j < 4; j++) {
      scl[j] = scp[j*16 + i16];
      if (qkv == 0) scl[j] *= 1.4426950408889634f;   // log2(e)
    }
    const float2* rt = rtab + i16;
#pragma unroll
    for (int i = 0; i < 2; i++) {
      f32x4 ssv = fzero;
#pragma unroll
      for (int j = 0; j < 4; j++)
#pragma unroll
        for (int r = 0; r < 4; r++) ssv[r] += acc[i][j][r]*acc[i][j][r];
#pragma unroll
      for (int d = 1; d < 16; d <<= 1)
#pragma unroll
        for (int r = 0; r < 4; r++) ssv[r] += __shfl_xor(ssv[r], d);
#pragma unroll
      for (int r = 0; r < 4; r++) {
        int m = m0 + i*16 + g*4 + r;
        int bb = m >> 10, ns = m & 1023;
        float rinv = rsqrtf(ssv[r] * (1.0f/64.0f) + 1e-6f);
        int2 pp = *(const int2*)(pos_ids + ((size_t)bb*NSEQ + ns)*2);
        float2 t0 = rt[pp.x*16];
        float2 t1 = rt[pp.y*16];
        float x0 = acc[i][0][r]*rinv*scl[0];
        float x1 = acc[i][1][r]*rinv*scl[1];
        float x2 = acc[i][2][r]*rinv*scl[2];
        float x3 = acc[i][3][r]*rinv*scl[3];
        size_t row = ((size_t)qkv*BHN + bb*NH + h)*NSEQ + ns;
        f16* ob = QKout + row*64;
        ob[i16]      = (f16)(x0*t0.x - x1*t0.y);
        ob[16 + i16] = (f16)(x1*t0.x + x0*t0.y);
        ob[32 + i16] = (f16)(x2*t1.x - x3*t1.y);
        ob[48 + i16] = (f16)(x3*t1.x + x2*t1.y);
      }
    }
  }
  }
}

// sigma: LDS K-row p holds physical kv sigma(p); bit layout p={u,b,g,g,c,c} -> {u,g,g,b,c,c}
__device__ __forceinline__ int sigma_perm(int p) {
  return (p & 0x20) | ((p & 0xC) << 1) | ((p & 0x10) >> 2) | (p & 3);
}

#define FM3(a,b,c) fmaxf(fmaxf(a,b),c)

// flash attention: 1D grid 768 (= 3 blocks/CU exactly, no drain tail),
// XCD-local: xcd=id&7 owns 12 bh x 8 qb of 128 q rows. 8 waves x 16 q rows,
// KV tile = 64. exp2-domain softmax; l via MFMA(P, ones).
__global__ __launch_bounds__(512) void attn_kernel(const f16* __restrict__ QKu,
                                                   const f16* __restrict__ Vtu,
                                                   f16* __restrict__ O) {
  const int id = blockIdx.x;                 // 768 = 8 xcd * 12 bh * 8 qb
  const int xcd = id & 7, idx = id >> 3;     // idx 0..95
  const int bh = xcd*12 + (idx >> 3);
  const int q0 = (idx & 7) * 128;
  const int tid = threadIdx.x, w = tid >> 6, l = tid & 63;
  const int g = l >> 4, i16 = l & 15;
  const int g4 = g*4;
  const int sw = i16 & 7;
  const int b = bh / NH, h = bh - b*NH;

  __shared__ __align__(16) f16 Ks[2*64*64];
  __shared__ __align__(16) f16 Vs[2*64*64];

  const f16* qrow = QKu + ((size_t)bh*NSEQ + q0 + w*16 + i16)*64;
  f16x8 q0f = *(const f16x8*)(qrow + g*8);
  f16x8 q1f = *(const f16x8*)(qrow + 32 + g*8);

  const char* Kb  = (const char*)(QKu + (size_t)(BHN + bh)*NSEQ*64);
  const char* Vtb = (const char*)(Vtu + (size_t)bh*64*1024);
  const int prow0 = w*8 + (l >> 3);          // 0..63: one issue covers all rows
  const int cl = (l & 7) ^ (l >> 3);
  const char* Ksrc = Kb + sigma_perm(prow0)*128 + cl*16;
  const char* Vsrc = Vtb + prow0*2048 + cl*16;

  const f32x4 fzero = {0.f, 0.f, 0.f, 0.f};
  const f16x8 vones = {(f16)1.f,(f16)1.f,(f16)1.f,(f16)1.f,
                       (f16)1.f,(f16)1.f,(f16)1.f,(f16)1.f};
  float mR = -1e30f;
  f32x4 o[4];
  f32x4 acc_l = fzero;
#pragma unroll
  for (int t = 0; t < 4; t++) o[t] = fzero;

  int cur = 0;
  {
    gload16(Ksrc, (char*)Ks + w*1024);
    gload16(Vsrc, (char*)Vs + w*1024);
  }
  __syncthreads();

  for (int t = 0; t < 16; ++t) {
    if (t < 15) {
      gload16(Ksrc + (t+1)*8192, (char*)Ks + (cur^1)*8192 + w*1024);
      gload16(Vsrc + (t+1)*128,  (char*)Vs + (cur^1)*8192 + w*1024);
    }
    const f16* Kc = Ks + cur*4096;
    const f16* Vc = Vs + cur*4096;

    f32x4 s[4] = {fzero, fzero, fzero, fzero};
    __builtin_amdgcn_s_setprio(1);
#pragma unroll
    for (int j = 0; j < 4; ++j) {
      const f16* kr = Kc + (j*16 + i16)*64;
      f16x8 k0 = *(const f16x8*)(kr + (g ^ sw)*8);
      f16x8 k1 = *(const f16x8*)(kr + ((g^4) ^ sw)*8);
      s[j] = MFMA(k0, q0f, s[j]);
      s[j] = MFMA(k1, q1f, s[j]);
    }
    __builtin_amdgcn_s_setprio(0);

    // row max (v_max3-friendly triples) + cross-lane reduce over the i16 group
    float t0m = FM3(s[0][0], s[0][1], s[0][2]);
    float t1m = FM3(s[0][3], s[1][0], s[1][1]);
    float t2m = FM3(s[1][2], s[1][3], s[2][0]);
    float t3m = FM3(s[2][1], s[2][2], s[2][3]);
    float t4m = FM3(s[3][0], s[3][1], s[3][2]);
    float tm = fmaxf(FM3(FM3(t0m, t1m, t2m), t3m, t4m), s[3][3]);
    tm = fmaxf(tm, __shfl_xor(tm, 16));
    tm = fmaxf(tm, __shfl_xor(tm, 32));
    if (__any(tm > mR + 11.5416f)) {         // defer-max, THR = 8*log2e
      float nm = fmaxf(mR, tm);
      float fac = __builtin_amdgcn_exp2f(mR - nm);
      mR = nm;
#pragma unroll
      for (int r = 0; r < 4; ++r) {
        float fr = __shfl(fac, g4 + r);
        o[0][r] *= fr; o[1][r] *= fr; o[2][r] *= fr; o[3][r] *= fr;
        acc_l[r] *= fr;
      }
    }
#pragma unroll
    for (int j = 0; j < 4; ++j)
#pragma unroll
      for (int r = 0; r < 4; ++r) s[j][r] = __builtin_amdgcn_exp2f(s[j][r] - mR);

    // packed cvt to the PV A-fragments
    union { h16x2 h[4]; f16x8 v; } u0, u1;
    u0.h[0] = __builtin_amdgcn_cvt_pkrtz(s[0][0], s[0][1]);
    u0.h[1] = __builtin_amdgcn_cvt_pkrtz(s[0][2], s[0][3]);
    u0.h[2] = __builtin_amdgcn_cvt_pkrtz(s[1][0], s[1][1]);
    u0.h[3] = __builtin_amdgcn_cvt_pkrtz(s[1][2], s[1][3]);
    u1.h[0] = __builtin_amdgcn_cvt_pkrtz(s[2][0], s[2][1]);
    u1.h[1] = __builtin_amdgcn_cvt_pkrtz(s[2][2], s[2][3]);
    u1.h[2] = __builtin_amdgcn_cvt_pkrtz(s[3][0], s[3][1]);
    u1.h[3] = __builtin_amdgcn_cvt_pkrtz(s[3][2], s[3][3]);
    f16x8 pa0 = u0.v, pa1 = u1.v;

    __builtin_amdgcn_s_setprio(1);
#pragma unroll
    for (int t2 = 0; t2 < 4; ++t2) {
      const f16* vr = Vc + (t2*16 + i16)*64;
      f16x8 bv0 = *(const f16x8*)(vr + (g ^ sw)*8);
      f16x8 bv1 = *(const f16x8*)(vr + ((g^4) ^ sw)*8);
      o[t2] = MFMA(pa0, bv0, o[t2]);
      o[t2] = MFMA(pa1, bv1, o[t2]);
    }
    acc_l = MFMA(pa0, vones, acc_l);     // row-sum l on the matrix pipe
    acc_l = MFMA(pa1, vones, acc_l);
    __builtin_amdgcn_s_setprio(0);

    __syncthreads();
    cur ^= 1;
  }

#pragma unroll
  for (int r = 0; r < 4; ++r) {
    float invl = 1.0f / acc_l[r];
    int q = q0 + w*16 + g4 + r;
    size_t base = ((size_t)(b*NSEQ + q))*DMODEL + h*DHD;
#pragma unroll
    for (int t2 = 0; t2 < 4; ++t2)
      O[base + t2*16 + i16] = (f16)(o[t2][r] * invl);
  }
}

extern "C" void kernel_launch(void* const* d_in, const int* in_sizes, int n_in,
                              void* d_out, int out_size, void* d_ws, size_t ws_size,
                              hipStream_t stream) {
  const float* hs = (const float*)d_in[0];
  const int*   pos = (const int*)d_in[1];
  const float* Wq = (const float*)d_in[2];
  const float* Wk = (const float*)d_in[3];
  const float* Wv = (const float*)d_in[4];
  const float* Wo = (const float*)d_in[5];
  const float* qs = (const float*)d_in[6];
  const float* ks = (const float*)d_in[7];

  const int nhs = 8192*768;       // 6291456
  const int nw  = 768*768;        // 589824

  char* p = (char*)d_ws;
  f16* Xf   = (f16*)p; p += (size_t)nhs*2;
  f16* Wf   = (f16*)p; p += (size_t)3*nw*2;         // Wq|Wk|Wv
  f16* Wof  = (f16*)p; p += (size_t)nw*2;
  f16* QKpk = (f16*)p; p += (size_t)2*ROWS_PER*64*2;
  f16* Vt   = (f16*)p; p += (size_t)ROWS_PER*64*2;
  f16* Ob   = (f16*)p; p += (size_t)nhs*2;
  float2* Rtab = (float2*)p; p += 512*sizeof(float2);

  cast_all_kernel<<<(nhs + 4*nw)/1024, 256, 0, stream>>>(hs, Wq, Wk, Wv, Wo,
                                                         Xf, Wf, Wof, Rtab, nhs, nw);

  gemm_bt<1><<<1152, 512, 0, stream>>>(Xf, Wf, nullptr, QKpk, Vt,
                                       pos, qs, ks, Rtab, 8192, 2304, 768);
  attn_kernel<<<768, 512, 0, stream>>>(QKpk, Vt, Ob);
  gemm_bt<0><<<768, 512, 0, stream>>>(Ob, Wof, (float*)d_out, nullptr, nullptr,
                                      nullptr, nullptr, nullptr, nullptr, 8192, 768, 768);
}